// Round 1
// baseline (179.175 us; speedup 1.0000x reference)
//
#include <hip/hip_runtime.h>
#include <math.h>

// SSIM loss, fused. Inputs: pred, target fp32 (64,1,512,512). Output: scalar fp32.
//
// Reformulation: S = u(X)+u(Y), D = u(X)-u(Y) where u is the unnormalize affine.
// Only 4 blurred channels needed:
//   muS = blur(S), muD = blur(D), PS = blur(S^2), PD = blur(D^2)
//   sigS = PS - muS^2, sigD = PD - muD^2
//   ssim = [(muS^2 - muD^2 + 2C1)/(muS^2 + muD^2 + 2C1)]
//        * [(sigS - sigD + 2C2)/(sigS + sigD + 2C2)]
// (identical to the 5-channel form: muS^2-muD^2 = 4 mu1 mu2, etc.)

#define WIN 11
#define IMG 512
#define OUTW 502            // 512 - 11 + 1
#define BAND 64             // output rows per block
#define RY 8                // output rows per chunk
#define COLS 520            // padded sV width (16B-aligned row stride)

constexpr float A_SC  = 8.0f / 37.0f;          // std / (max-min)
constexpr float TWO_B = 2.0f * (15.5f / 37.0f); // 2*(mean-min)/(max-min)
constexpr float TWO_C1 = 2.0f * 1e-4f;
constexpr float TWO_C2 = 2.0f * 9e-4f;

__global__ __launch_bounds__(512, 4)
void ssim_main(const float* __restrict__ X, const float* __restrict__ Y,
               float* __restrict__ ws)
{
    // 4 ch * 8 rows * 520 cols * 4B = 66,560 B -> 2 blocks/CU
    __shared__ __align__(16) float sV[4][RY][COLS];
    __shared__ float sW[WIN];
    __shared__ float sRed[8];

    const int tid  = threadIdx.x;
    const int band = blockIdx.x;
    const int b    = blockIdx.y;
    const int y0   = band * BAND;
    const size_t base = (size_t)b * IMG * IMG;

    // Gaussian window in fp64 (matches reference: float64 -> normalize -> float32)
    if (tid == 0) {
        double g[WIN]; double sum = 0.0;
        for (int k = 0; k < WIN; ++k) { double c = k - 5; g[k] = exp(-(c * c) / 4.5); sum += g[k]; }
        for (int k = 0; k < WIN; ++k) sW[k] = (float)(g[k] / sum);
    }
    __syncthreads();
    float w[WIN];
    #pragma unroll
    for (int k = 0; k < WIN; ++k) w[k] = sW[k];

    const int x = tid;        // column owned in vertical pass (0..511)
    const int r = tid >> 6;   // row slot in horizontal pass: wave index 0..7
    const int s = tid & 63;   // group slot within row

    float acc = 0.0f;

    for (int c = 0; c < BAND / RY; ++c) {
        const int ybase = y0 + c * RY;
        if (ybase >= OUTW) break;   // block-uniform

        // ---- vertical pass: stream 18 input rows, scatter into 4x8 register sums
        float vs[RY], vd[RY], vss[RY], vdd[RY];
        #pragma unroll
        for (int rr = 0; rr < RY; ++rr) { vs[rr] = 0.f; vd[rr] = 0.f; vss[rr] = 0.f; vdd[rr] = 0.f; }

        #pragma unroll
        for (int j = 0; j < RY + WIN - 1; ++j) {
            int yi = ybase + j; yi = yi < IMG - 1 ? yi : IMG - 1; // clamp feeds only masked rows
            const float xv = X[base + (size_t)yi * IMG + x];
            const float yv = Y[base + (size_t)yi * IMG + x];
            const float sv = fmaf(xv + yv, A_SC, TWO_B);  // u(x)+u(y)
            const float dv = (xv - yv) * A_SC;            // u(x)-u(y)
            const float ssv = sv * sv, ddv = dv * dv;
            #pragma unroll
            for (int rr = 0; rr < RY; ++rr) {
                const int k = j - rr;
                if (k >= 0 && k < WIN) {
                    const float wk = w[k];
                    vs[rr]  = fmaf(wk, sv,  vs[rr]);
                    vd[rr]  = fmaf(wk, dv,  vd[rr]);
                    vss[rr] = fmaf(wk, ssv, vss[rr]);
                    vdd[rr] = fmaf(wk, ddv, vdd[rr]);
                }
            }
        }

        __syncthreads();   // previous chunk's readers done
        #pragma unroll
        for (int rr = 0; rr < RY; ++rr) {
            sV[0][rr][x] = vs[rr];
            sV[1][rr][x] = vd[rr];
            sV[2][rr][x] = vss[rr];
            sV[3][rr][x] = vdd[rr];
        }
        __syncthreads();

        // ---- horizontal pass: wave r handles row r; lane s handles 4-wide groups
        // at x0 = 4*s and 4*(s+64). Lane stride 16B -> conflict-free ds_read_b128.
        const int yo = ybase + r;
        const bool rowok = (yo < OUTW);
        #pragma unroll
        for (int gi = 0; gi < 2; ++gi) {
            const int x0 = 4 * (s + 64 * gi);
            if (rowok && x0 < OUTW) {
                float H[4][4];
                #pragma unroll
                for (int ch = 0; ch < 4; ++ch) {
                    const float4* p = (const float4*)&sV[ch][r][x0];
                    const float4 q0 = p[0], q1 = p[1], q2 = p[2], q3 = p[3];
                    const float win[16] = {q0.x,q0.y,q0.z,q0.w, q1.x,q1.y,q1.z,q1.w,
                                           q2.x,q2.y,q2.z,q2.w, q3.x,q3.y,q3.z,q3.w};
                    #pragma unroll
                    for (int i = 0; i < 4; ++i) {
                        float a = 0.f;
                        #pragma unroll
                        for (int k = 0; k < WIN; ++k) a = fmaf(w[k], win[i + k], a);
                        H[ch][i] = a;
                    }
                }
                #pragma unroll
                for (int i = 0; i < 4; ++i) {
                    if (x0 + i < OUTW) {
                        const float mS = H[0][i], mD = H[1][i], PS = H[2][i], PD = H[3][i];
                        const float mS2 = mS * mS, mD2 = mD * mD;
                        const float sS = PS - mS2, sD = PD - mD2;
                        const float num = (mS2 - mD2 + TWO_C1) * (sS - sD + TWO_C2);
                        const float den = (mS2 + mD2 + TWO_C1) * (sS + sD + TWO_C2);
                        acc += num * __builtin_amdgcn_rcpf(den);
                    }
                }
            }
        }
    }

    // ---- block reduction -> one atomic per (band, image)
    #pragma unroll
    for (int off = 32; off > 0; off >>= 1) acc += __shfl_down(acc, off, 64);
    if ((tid & 63) == 0) sRed[tid >> 6] = acc;
    __syncthreads();
    if (tid == 0) {
        float t = 0.f;
        #pragma unroll
        for (int i = 0; i < 8; ++i) t += sRed[i];
        atomicAdd(&ws[b], t);
    }
}

__global__ void ssim_finalize(const float* __restrict__ ws, float* __restrict__ out)
{
    const int t = threadIdx.x; // 64 threads, one wave
    float v = ws[t] * (1.0f / (OUTW * OUTW));
    v = v > 0.f ? v : 0.f;     // relu(per-image mean)
    #pragma unroll
    for (int off = 32; off > 0; off >>= 1) v += __shfl_down(v, off, 64);
    if (t == 0) out[0] = v * (1.0f / 64.0f);
}

extern "C" void kernel_launch(void* const* d_in, const int* in_sizes, int n_in,
                              void* d_out, int out_size, void* d_ws, size_t ws_size,
                              hipStream_t stream)
{
    const float* pred   = (const float*)d_in[0];
    const float* target = (const float*)d_in[1];
    float* out = (float*)d_out;
    float* ws  = (float*)d_ws;

    hipMemsetAsync(ws, 0, 64 * sizeof(float), stream);  // ws poisoned 0xAA each call
    ssim_main<<<dim3(8, 64), 512, 0, stream>>>(pred, target, ws);
    ssim_finalize<<<1, 64, 0, stream>>>(ws, out);
}

// Round 2
// 169.978 us; speedup vs baseline: 1.0541x; 1.0541x over previous
//
#include <hip/hip_runtime.h>
#include <math.h>

// SSIM loss, fused. Inputs: pred, target fp32 (64,1,512,512). Output: scalar fp32.
//
// S = u(X)+u(Y), D = u(X)-u(Y);  4 blurred channels:
//   muS=blur(S), muD=blur(D), PS=blur(S^2), PD=blur(D^2)
//   ssim = [(muS^2-muD^2+2C1)/(muS^2+muD^2+2C1)] * [(PS-muS^2-PD+muD^2+2C2)/(PS-muS^2+PD-muD^2+2C2)]
//
// R2: rolling 10-row prep ring in registers (vertical pass loads each input row
// once), 32-bit global indexing. Chunk loop deliberately NOT unrolled (I$).

#define WIN 11
#define IMG 512
#define OUTW 502            // 512 - 11 + 1
#define BAND 64             // output rows per block
#define RY 8                // output rows per chunk
#define COLS 520            // padded sV row stride (floats)

constexpr float A_SC  = 8.0f / 37.0f;           // std / (max-min)
constexpr float TWO_B = 2.0f * (15.5f / 37.0f); // 2*(mean-min)/(max-min)
constexpr float TWO_C1 = 2.0f * 1e-4f;
constexpr float TWO_C2 = 2.0f * 9e-4f;

__global__ __launch_bounds__(512, 4)
void ssim_main(const float* __restrict__ X, const float* __restrict__ Y,
               float* __restrict__ ws)
{
    // 4 ch * 8 rows * 520 cols * 4B = 66,560 B -> 2 blocks/CU
    __shared__ __align__(16) float sV[4][RY][COLS];
    __shared__ float sW[WIN];
    __shared__ float sRed[8];

    const int tid  = threadIdx.x;
    const int band = blockIdx.x;
    const int b    = blockIdx.y;
    const int y0   = band * BAND;

    if (tid == 0) {
        double g[WIN]; double sum = 0.0;
        for (int k = 0; k < WIN; ++k) { double c = k - 5; g[k] = exp(-(c * c) / 4.5); sum += g[k]; }
        for (int k = 0; k < WIN; ++k) sW[k] = (float)(g[k] / sum);
    }
    __syncthreads();
    float w[WIN];
    #pragma unroll
    for (int k = 0; k < WIN; ++k) w[k] = sW[k];

    const float* __restrict__ Xb = X + (size_t)b * (IMG * (size_t)IMG);
    const float* __restrict__ Yb = Y + (size_t)b * (IMG * (size_t)IMG);

    const int x = tid;        // column owned in vertical pass
    const int r = tid >> 6;   // horizontal pass: wave index = row slot
    const int s = tid & 63;

    float acc = 0.0f;

    // Rolling prep ring: ps[i] holds row (ybase + i) for the CURRENT chunk, i=0..9.
    float ps[10], pd[10], pss[10], pdd[10];
    #pragma unroll
    for (int i = 0; i < 10; ++i) {
        const uint32_t idx = (uint32_t)(y0 + i) * IMG + (uint32_t)x;
        const float xv = Xb[idx], yv = Yb[idx];
        const float sv = fmaf(xv + yv, A_SC, TWO_B);
        const float dv = (xv - yv) * A_SC;
        ps[i] = sv; pd[i] = dv; pss[i] = sv * sv; pdd[i] = dv * dv;
    }

    #pragma unroll 1
    for (int c = 0; c < BAND / RY; ++c) {
        const int ybase = y0 + c * RY;
        if (ybase < OUTW) {   // block-uniform
            float vs[RY], vd[RY], vss[RY], vdd[RY];
            #pragma unroll
            for (int rr = 0; rr < RY; ++rr) { vs[rr] = 0.f; vd[rr] = 0.f; vss[rr] = 0.f; vdd[rr] = 0.f; }

            // kept rows j = 0..9 (from ring)
            #pragma unroll
            for (int j = 0; j < 10; ++j) {
                const float a0 = ps[j], a1 = pd[j], a2 = pss[j], a3 = pdd[j];
                #pragma unroll
                for (int rr = 0; rr < RY; ++rr) {
                    const int k = j - rr;
                    if (k >= 0 && k < WIN) {
                        const float wk = w[k];
                        vs[rr]  = fmaf(wk, a0, vs[rr]);
                        vd[rr]  = fmaf(wk, a1, vd[rr]);
                        vss[rr] = fmaf(wk, a2, vss[rr]);
                        vdd[rr] = fmaf(wk, a3, vdd[rr]);
                    }
                }
            }
            // save ring tail before overwriting (rows ybase+8, ybase+9)
            const float t0s = ps[8], t0d = pd[8], t0ss = pss[8], t0dd = pdd[8];
            const float t1s = ps[9], t1d = pd[9], t1ss = pss[9], t1dd = pdd[9];
            // fresh rows j = 10..17: load once, scatter, and park in ring slots 2..9
            #pragma unroll
            for (int jj = 0; jj < 8; ++jj) {
                const int j = 10 + jj;
                int yi = ybase + j; yi = yi < IMG - 1 ? yi : IMG - 1; // clamp feeds only masked rows
                const uint32_t idx = (uint32_t)yi * IMG + (uint32_t)x;
                const float xv = Xb[idx], yv = Yb[idx];
                const float sv = fmaf(xv + yv, A_SC, TWO_B);
                const float dv = (xv - yv) * A_SC;
                const float ssv = sv * sv, ddv = dv * dv;
                #pragma unroll
                for (int rr = 0; rr < RY; ++rr) {
                    const int k = j - rr;
                    if (k >= 0 && k < WIN) {
                        const float wk = w[k];
                        vs[rr]  = fmaf(wk, sv,  vs[rr]);
                        vd[rr]  = fmaf(wk, dv,  vd[rr]);
                        vss[rr] = fmaf(wk, ssv, vss[rr]);
                        vdd[rr] = fmaf(wk, ddv, vdd[rr]);
                    }
                }
                ps[2 + jj] = sv; pd[2 + jj] = dv; pss[2 + jj] = ssv; pdd[2 + jj] = ddv;
            }
            // rotate: next chunk's rows ybase+8, ybase+9 -> slots 0,1
            ps[0] = t0s; pd[0] = t0d; pss[0] = t0ss; pdd[0] = t0dd;
            ps[1] = t1s; pd[1] = t1d; pss[1] = t1ss; pdd[1] = t1dd;

            __syncthreads();   // previous chunk's readers done
            #pragma unroll
            for (int rr = 0; rr < RY; ++rr) {
                sV[0][rr][x] = vs[rr];
                sV[1][rr][x] = vd[rr];
                sV[2][rr][x] = vss[rr];
                sV[3][rr][x] = vdd[rr];
            }
            __syncthreads();

            // horizontal: wave r -> row r; lane s -> 4-wide groups at 4*s, 4*(s+64)
            // lane stride 16B -> 2-way bank aliasing only (free)
            const int yo = ybase + r;
            const bool rowok = (yo < OUTW);
            const float* __restrict__ rbase = &sV[0][r][0];  // ch stride RY*COLS floats
            #pragma unroll
            for (int gi = 0; gi < 2; ++gi) {
                const int x0 = 4 * (s + 64 * gi);
                if (rowok && x0 < OUTW) {
                    float H[4][4];
                    #pragma unroll
                    for (int ch = 0; ch < 4; ++ch) {
                        const float4* p = (const float4*)(rbase + ch * (RY * COLS) + x0);
                        const float4 q0 = p[0], q1 = p[1], q2 = p[2], q3 = p[3];
                        const float win[16] = {q0.x,q0.y,q0.z,q0.w, q1.x,q1.y,q1.z,q1.w,
                                               q2.x,q2.y,q2.z,q2.w, q3.x,q3.y,q3.z,q3.w};
                        #pragma unroll
                        for (int i = 0; i < 4; ++i) {
                            float a = 0.f;
                            #pragma unroll
                            for (int k = 0; k < WIN; ++k) a = fmaf(w[k], win[i + k], a);
                            H[ch][i] = a;
                        }
                    }
                    #pragma unroll
                    for (int i = 0; i < 4; ++i) {
                        if (x0 + i < OUTW) {
                            const float mS = H[0][i], mD = H[1][i], PS = H[2][i], PD = H[3][i];
                            const float mS2 = mS * mS, mD2 = mD * mD;
                            const float sS = PS - mS2, sD = PD - mD2;
                            const float num = (mS2 - mD2 + TWO_C1) * (sS - sD + TWO_C2);
                            const float den = (mS2 + mD2 + TWO_C1) * (sS + sD + TWO_C2);
                            acc = fmaf(num, __builtin_amdgcn_rcpf(den), acc);
                        }
                    }
                }
            }
        }
    }

    // block reduction -> one atomic per image
    #pragma unroll
    for (int off = 32; off > 0; off >>= 1) acc += __shfl_down(acc, off, 64);
    if ((tid & 63) == 0) sRed[tid >> 6] = acc;
    __syncthreads();
    if (tid == 0) {
        float t = 0.f;
        #pragma unroll
        for (int i = 0; i < 8; ++i) t += sRed[i];
        atomicAdd(&ws[b], t);
    }
}

__global__ void ssim_finalize(const float* __restrict__ ws, float* __restrict__ out)
{
    const int t = threadIdx.x; // one wave
    float v = ws[t] * (1.0f / (502.0f * 502.0f));
    v = v > 0.f ? v : 0.f;     // relu(per-image mean)
    #pragma unroll
    for (int off = 32; off > 0; off >>= 1) v += __shfl_down(v, off, 64);
    if (t == 0) out[0] = v * (1.0f / 64.0f);
}

extern "C" void kernel_launch(void* const* d_in, const int* in_sizes, int n_in,
                              void* d_out, int out_size, void* d_ws, size_t ws_size,
                              hipStream_t stream)
{
    const float* pred   = (const float*)d_in[0];
    const float* target = (const float*)d_in[1];
    float* out = (float*)d_out;
    float* ws  = (float*)d_ws;

    hipMemsetAsync(ws, 0, 64 * sizeof(float), stream);  // ws poisoned 0xAA each call
    ssim_main<<<dim3(8, 64), 512, 0, stream>>>(pred, target, ws);
    ssim_finalize<<<1, 64, 0, stream>>>(ws, out);
}

// Round 3
// 162.816 us; speedup vs baseline: 1.1005x; 1.0440x over previous
//
#include <hip/hip_runtime.h>
#include <math.h>

// SSIM loss, fused. Inputs: pred, target fp32 (64,1,512,512). Output: scalar fp32.
//
// S = u(X)+u(Y), D = u(X)-u(Y);  4 blurred channels:
//   muS=blur(S), muD=blur(D), PS=blur(S^2), PD=blur(D^2)
//   ssim = [(muS^2-muD^2+2C1)/(muS^2+muD^2+2C1)] * [(PS-muS^2-PD+muD^2+2C2)/(PS-muS^2+PD-muD^2+2C2)]
//
// R3: packed fp32 (v_pk_fma_f32) — channels paired as float2 {s,d} / {s2,d2}
// throughout vertical scatter, horizontal conv, prep, epilogue. Register ring
// keeps only {s,d} (s2,d2 recomputed: 1 pk_mul/row). LDS: interleaved pairs;
// vertical b64 writes conflict-free; horizontal b128 reads at 32B lane stride
// = 2-way conflict (acceptable vs halved VALU issue).

typedef float v2f __attribute__((ext_vector_type(2)));

#define WIN 11
#define IMG 512
#define OUTW 502            // 512 - 11 + 1
#define BAND 64             // output rows per block
#define RY 8                // output rows per chunk
#define COLS2 516           // float2 columns per row (512 + 4 pad; reads reach col 515)

constexpr float A_SC  = 8.0f / 37.0f;           // std / (max-min)
constexpr float TWO_B = 2.0f * (15.5f / 37.0f); // 2*(mean-min)/(max-min)
constexpr float TWO_C1 = 2.0f * 1e-4f;
constexpr float TWO_C2 = 2.0f * 9e-4f;

__global__ __launch_bounds__(512, 4)
void ssim_main(const float* __restrict__ X, const float* __restrict__ Y,
               float* __restrict__ ws)
{
    // 2 pair-channels * 8 rows * 516 cols * 8B = 66,048 B -> 2 blocks/CU
    __shared__ __align__(16) v2f sP[2][RY][COLS2];
    __shared__ float sW[WIN];
    __shared__ float sRed[8];

    const int tid  = threadIdx.x;
    const int band = blockIdx.x;
    const int b    = blockIdx.y;
    const int y0   = band * BAND;

    if (tid == 0) {
        double g[WIN]; double sum = 0.0;
        for (int k = 0; k < WIN; ++k) { double c = k - 5; g[k] = exp(-(c * c) / 4.5); sum += g[k]; }
        for (int k = 0; k < WIN; ++k) sW[k] = (float)(g[k] / sum);
    }
    __syncthreads();
    float w[WIN];
    #pragma unroll
    for (int k = 0; k < WIN; ++k) w[k] = sW[k];

    const float* __restrict__ Xb = X + (size_t)b * (IMG * (size_t)IMG);
    const float* __restrict__ Yb = Y + (size_t)b * (IMG * (size_t)IMG);

    const int x = tid;        // column owned in vertical pass
    const int r = tid >> 6;   // horizontal pass: wave index = row slot
    const int s = tid & 63;

    float acc = 0.0f;

    // Rolling prep ring: psd[i] = {s,d} of row (ybase + i), i=0..9.
    v2f psd[10];
    #pragma unroll
    for (int i = 0; i < 10; ++i) {
        const uint32_t idx = (uint32_t)(y0 + i) * IMG + (uint32_t)x;
        const float xv = Xb[idx], yv = Yb[idx];
        v2f t; t.x = fmaf(xv + yv, A_SC, TWO_B); t.y = (xv - yv) * A_SC;
        psd[i] = t;
    }

    #pragma unroll 1
    for (int c = 0; c < BAND / RY; ++c) {
        const int ybase = y0 + c * RY;
        if (ybase < OUTW) {   // block-uniform
            v2f vsd[RY], vq[RY];
            #pragma unroll
            for (int rr = 0; rr < RY; ++rr) { vsd[rr] = (v2f)0.0f; vq[rr] = (v2f)0.0f; }

            // kept rows j = 0..9 (from ring); recompute squares (1 pk_mul)
            #pragma unroll
            for (int j = 0; j < 10; ++j) {
                const v2f a = psd[j];
                const v2f q = a * a;
                #pragma unroll
                for (int rr = 0; rr < RY; ++rr) {
                    const int k = j - rr;
                    if (k >= 0 && k < WIN) {
                        const float wk = w[k];
                        vsd[rr] += wk * a;   // -> v_pk_fma_f32 (ffp-contract)
                        vq[rr]  += wk * q;
                    }
                }
            }
            const v2f t0 = psd[8], t1 = psd[9];
            // fresh rows j = 10..17: load once, scatter, park in ring slots 2..9
            #pragma unroll
            for (int jj = 0; jj < 8; ++jj) {
                const int j = 10 + jj;
                int yi = ybase + j; yi = yi < IMG - 1 ? yi : IMG - 1; // clamp feeds only masked rows
                const uint32_t idx = (uint32_t)yi * IMG + (uint32_t)x;
                const float xv = Xb[idx], yv = Yb[idx];
                v2f a; a.x = fmaf(xv + yv, A_SC, TWO_B); a.y = (xv - yv) * A_SC;
                const v2f q = a * a;
                #pragma unroll
                for (int rr = 0; rr < RY; ++rr) {
                    const int k = j - rr;
                    if (k >= 0 && k < WIN) {
                        const float wk = w[k];
                        vsd[rr] += wk * a;
                        vq[rr]  += wk * q;
                    }
                }
                psd[2 + jj] = a;
            }
            psd[0] = t0; psd[1] = t1;   // rows ybase+8, ybase+9 -> next chunk slots 0,1

            __syncthreads();   // previous chunk's readers done
            #pragma unroll
            for (int rr = 0; rr < RY; ++rr) {
                sP[0][rr][x] = vsd[rr];  // ds_write_b64, conflict-free
                sP[1][rr][x] = vq[rr];
            }
            __syncthreads();

            // horizontal: wave r -> row r; lane s -> 4-wide groups at 4*s, 4*(s+64)
            const int yo = ybase + r;
            const bool rowok = (yo < OUTW);
            #pragma unroll
            for (int gi = 0; gi < 2; ++gi) {
                const int x0 = 4 * (s + 64 * gi);
                if (rowok && x0 < OUTW) {
                    v2f Hsd[4], Hq[4];
                    #pragma unroll
                    for (int p = 0; p < 2; ++p) {
                        // 16 pair-columns via 8 x b128 (x0 even -> 16B aligned)
                        const float4* q4 = (const float4*)&sP[p][r][x0];
                        v2f win2[16];
                        #pragma unroll
                        for (int j = 0; j < 8; ++j) {
                            const float4 qq = q4[j];
                            v2f lo; lo.x = qq.x; lo.y = qq.y;
                            v2f hi; hi.x = qq.z; hi.y = qq.w;
                            win2[2 * j] = lo; win2[2 * j + 1] = hi;
                        }
                        #pragma unroll
                        for (int i = 0; i < 4; ++i) {
                            v2f a = (v2f)0.0f;
                            #pragma unroll
                            for (int k = 0; k < WIN; ++k) a += w[k] * win2[i + k];
                            if (p == 0) Hsd[i] = a; else Hq[i] = a;
                        }
                    }
                    #pragma unroll
                    for (int i = 0; i < 4; ++i) {
                        if (x0 + i < OUTW) {
                            const v2f m2 = Hsd[i] * Hsd[i];   // {mS2, mD2}
                            const v2f sg = Hq[i] - m2;        // {sS, sD}
                            const float na = m2.x - m2.y + TWO_C1;
                            const float da = m2.x + m2.y + TWO_C1;
                            const float nb = sg.x - sg.y + TWO_C2;
                            const float db = sg.x + sg.y + TWO_C2;
                            acc = fmaf(na * nb, __builtin_amdgcn_rcpf(da * db), acc);
                        }
                    }
                }
            }
        }
    }

    // block reduction -> one atomic per image
    #pragma unroll
    for (int off = 32; off > 0; off >>= 1) acc += __shfl_down(acc, off, 64);
    if ((tid & 63) == 0) sRed[tid >> 6] = acc;
    __syncthreads();
    if (tid == 0) {
        float t = 0.f;
        #pragma unroll
        for (int i = 0; i < 8; ++i) t += sRed[i];
        atomicAdd(&ws[b], t);
    }
}

__global__ void ssim_finalize(const float* __restrict__ ws, float* __restrict__ out)
{
    const int t = threadIdx.x; // one wave
    float v = ws[t] * (1.0f / (502.0f * 502.0f));
    v = v > 0.f ? v : 0.f;     // relu(per-image mean)
    #pragma unroll
    for (int off = 32; off > 0; off >>= 1) v += __shfl_down(v, off, 64);
    if (t == 0) out[0] = v * (1.0f / 64.0f);
}

extern "C" void kernel_launch(void* const* d_in, const int* in_sizes, int n_in,
                              void* d_out, int out_size, void* d_ws, size_t ws_size,
                              hipStream_t stream)
{
    const float* pred   = (const float*)d_in[0];
    const float* target = (const float*)d_in[1];
    float* out = (float*)d_out;
    float* ws  = (float*)d_ws;

    hipMemsetAsync(ws, 0, 64 * sizeof(float), stream);  // ws poisoned 0xAA each call
    ssim_main<<<dim3(8, 64), 512, 0, stream>>>(pred, target, ws);
    ssim_finalize<<<1, 64, 0, stream>>>(ws, out);
}